// Round 7
// baseline (237.738 us; speedup 1.0000x reference)
//
#include <hip/hip_runtime.h>
#include <math.h>

#define R_ 2048
#define A_ 16384
#define E_ 131072
#define K_ 48
#define NREL_ 7

typedef __attribute__((ext_vector_type(8))) short bfrag8;
typedef __attribute__((ext_vector_type(4))) float f32x4v;

__device__ __forceinline__ unsigned short bf16rne(float f) {
    unsigned u = __builtin_bit_cast(unsigned, f);
    u += 0x7FFFu + ((u >> 16) & 1u);
    return (unsigned short)(u >> 16);
}

__device__ __forceinline__ float dist2(float x, float y, float z,
                                       float cx, float cy, float cz) {
    float dx = x - cx, dy = y - cy, dz = z - cz;
    return fmaf(dx, dx, fmaf(dy, dy, dz * dz));   // deterministic everywhere
}

// ---------------------------------------------------------------- prep: weights->bf16 + res_feat
__global__ __launch_bounds__(256) void k_prep(
    const float* __restrict__ Wconv, const float* __restrict__ Wself,
    const float* __restrict__ We1, const float* __restrict__ We2,
    const float* __restrict__ W1,
    const float* __restrict__ node, const float* __restrict__ Wres,
    const float* __restrict__ bres,
    unsigned short* __restrict__ Bt1, unsigned short* __restrict__ Bt2,
    unsigned short* __restrict__ Bt3, unsigned short* __restrict__ W1t,
    float* __restrict__ resfeat, float* __restrict__ bufA)
{
    int id = blockIdx.x * 256 + threadIdx.x;
    if (id < 262144) {
        int k = id & 511, n = id >> 9;
        float v = (k < 448) ? Wconv[k * 512 + n] : Wself[(k - 448) * 512 + n];
        Bt1[n * 512 + k] = bf16rne(v);
    } else if (id < 655360) {
        int rel = id - 262144;
        int k = rel % 768, n = rel / 768;
        Bt2[n * 768 + k] = bf16rne(We1[k * 512 + n]);
    } else if (id < 917504) {
        int rel = id - 655360;
        int k = rel & 511, n = rel >> 9;
        Bt3[n * 512 + k] = bf16rne(We2[k * 512 + n]);
    } else if (id < 925696) {
        int rel = id - 917504;
        int k = rel & 63, n = rel >> 6;     // n<128, k<64
        W1t[n * 64 + k] = bf16rne(W1[k * 128 + n]);
    } else if (id < 1056768) {
        int rel = id - 925696;
        int r = rel >> 6, c = rel & 63;
        float s = bres[c];
#pragma unroll
        for (int i = 0; i < 21; ++i) s += node[r * 21 + i] * Wres[i * 64 + c];
        resfeat[r * 64 + c] = s;
        bufA[(size_t)r * 512 + 448 + c] = s;
    }
}

// ---------------------------------------------------------------- edge CSR pipeline (replaces atomic scatter)
__global__ __launch_bounds__(256) void k_hist(
    const int* __restrict__ edst, const int* __restrict__ erel,
    int* __restrict__ cnt)
{
    int e = blockIdx.x * 256 + threadIdx.x;
    atomicAdd(&cnt[edst[e] * NREL_ + erel[e]], 1);
}

__global__ __launch_bounds__(1024) void k_scan(
    const int* __restrict__ cnt, int* __restrict__ offs, int* __restrict__ cursor)
{
    __shared__ int part[1024];
    int t = threadIdx.x;
    int base = t * 14;                    // 1024 * 14 = 14336 = R*NREL
    int loc[14];
    int s = 0;
#pragma unroll
    for (int i = 0; i < 14; ++i) { loc[i] = s; s += cnt[base + i]; }
    part[t] = s;
    __syncthreads();
    for (int st = 1; st < 1024; st <<= 1) {
        int v = (t >= st) ? part[t - st] : 0;
        __syncthreads();
        part[t] += v;
        __syncthreads();
    }
    int excl = (t == 0) ? 0 : part[t - 1];
#pragma unroll
    for (int i = 0; i < 14; ++i) {
        int o = excl + loc[i];
        offs[base + i] = o;
        cursor[base + i] = o;
    }
    if (t == 1023) offs[14336] = part[1023];
}

__global__ __launch_bounds__(256) void k_scatter(
    const int* __restrict__ esrc, const int* __restrict__ edst,
    const int* __restrict__ erel, int* __restrict__ cursor,
    int* __restrict__ eord)
{
    int e = blockIdx.x * 256 + threadIdx.x;
    int seg = edst[e] * NREL_ + erel[e];
    int p = atomicAdd(&cursor[seg], 1);
    eord[p] = esrc[e];                    // store src directly
}

// block per dest: 4 rel-groups x 64 channels; atomic-free segment sums
__global__ __launch_bounds__(256) void k_gather(
    const int* __restrict__ offs, const int* __restrict__ eord,
    const float* __restrict__ resfeat, float* __restrict__ bufA)
{
    int r = blockIdx.x;
    int c = threadIdx.x & 63, rg = threadIdx.x >> 6;
    for (int rel = rg; rel < NREL_; rel += 4) {
        int seg = r * NREL_ + rel;
        int j0 = offs[seg], j1 = offs[seg + 1];
        float acc = 0.f;
        for (int j = j0; j < j1; ++j)
            acc += resfeat[eord[j] * 64 + c];
        bufA[(size_t)r * 512 + rel * 64 + c] = acc;
    }
}

// ---------------------------------------------------------------- ball query: d2-space bins, LDS bin cache
__global__ __launch_bounds__(256) void k_ball(
    const float* __restrict__ pos, const int* __restrict__ ca_idx,
    int* __restrict__ nbr)
{
    __shared__ unsigned binsw[4096];     // 16KB: 8-bit bin per atom
    __shared__ unsigned hist[256];
    __shared__ unsigned hist2[256];
    __shared__ int sc[256];
    __shared__ float candd[128];
    __shared__ int candi[128];
    __shared__ unsigned s_cnt, s_ccnt;
    __shared__ int s_list[64];
    __shared__ int sB, sNeed, sB2, sNeed2, sTotal;

    int tid = threadIdx.x;
    int r = blockIdx.x;
    int ca = ca_idx[r];
    float cx = pos[ca * 3 + 0], cy = pos[ca * 3 + 1], cz = pos[ca * 3 + 2];

    hist[tid] = 0u;
    if (tid == 0) { s_cnt = 0u; s_ccnt = 0u; }
    __syncthreads();

    // ---- pass 1: d2, bin byte -> LDS, histogram
    for (int it = 0; it < 16; ++it) {
        int a0 = it * 1024 + tid * 4;
        const float4* p = (const float4*)(pos + (size_t)a0 * 3);
        float4 p0 = p[0], p1 = p[1], p2 = p[2];
        float xs[4] = { p0.x, p0.w, p1.z, p2.y };
        float ys[4] = { p0.y, p1.x, p1.w, p2.z };
        float zs[4] = { p0.z, p1.y, p2.x, p2.w };
        unsigned pack = 0;
#pragma unroll
        for (int q = 0; q < 4; ++q) {
            float d2 = dist2(xs[q], ys[q], zs[q], cx, cy, cz);
            int b = 255;
            if (d2 < 100.0f) {
                b = (int)(d2 * 2.56f); if (b > 254) b = 254;
                atomicAdd(&hist[b], 1u);
            }
            pack |= (unsigned)b << (q * 8);
        }
        binsw[it * 256 + tid] = pack;
    }
    __syncthreads();

    // ---- scan
    sc[tid] = (int)hist[tid];
    __syncthreads();
    for (int s = 1; s < 256; s <<= 1) {
        int v = (tid >= s) ? sc[tid - s] : 0;
        __syncthreads();
        sc[tid] += v;
        __syncthreads();
    }
    if (tid == 0) sTotal = sc[255];
    if (sc[tid] >= K_ && (tid == 0 || sc[tid - 1] < K_)) {
        sB = tid;
        sNeed = K_ - (sc[tid] - (int)hist[tid]);
    }
    __syncthreads();

    int mode = (sTotal <= K_) ? 0 : (((int)hist[sB] > 128) ? 2 : 1);

    if (mode <= 1) {
        // ---- selection from LDS bins
        int B = (mode == 0) ? 255 : sB;
        for (int it = 0; it < 16; ++it) {
            unsigned pack = binsw[it * 256 + tid];
            int a0 = it * 1024 + tid * 4;
#pragma unroll
            for (int q = 0; q < 4; ++q) {
                int b = (pack >> (q * 8)) & 255;
                if (b < B) { unsigned pp = atomicAdd(&s_cnt, 1u); s_list[pp] = a0 + q; }
                else if (b == B && mode == 1) {
                    unsigned c = atomicAdd(&s_ccnt, 1u);
                    if (c < 128u) candi[c] = a0 + q;
                }
            }
        }
    } else {
        // ---- mode 2: refine boundary bin in d2-subspace (recompute only byte==B atoms)
        int B = sB;
        float lo2 = B * 0.390625f;
        hist2[tid] = 0u;
        __syncthreads();
        for (int it = 0; it < 16; ++it) {
            unsigned pack = binsw[it * 256 + tid];
            int a0 = it * 1024 + tid * 4;
#pragma unroll
            for (int q = 0; q < 4; ++q) {
                if (((pack >> (q * 8)) & 255) == (unsigned)B) {
                    int a = a0 + q;
                    float d2 = dist2(pos[a * 3], pos[a * 3 + 1], pos[a * 3 + 2], cx, cy, cz);
                    int k2 = (int)((d2 - lo2) * 655.36f);
                    if (k2 < 0) k2 = 0; if (k2 > 255) k2 = 255;
                    atomicAdd(&hist2[k2], 1u);
                }
            }
        }
        __syncthreads();
        sc[tid] = (int)hist2[tid];
        __syncthreads();
        for (int s = 1; s < 256; s <<= 1) {
            int v = (tid >= s) ? sc[tid - s] : 0;
            __syncthreads();
            sc[tid] += v;
            __syncthreads();
        }
        if (sc[tid] >= sNeed && (tid == 0 || sc[tid - 1] < sNeed)) {
            sB2 = tid;
            sNeed2 = sNeed - (sc[tid] - (int)hist2[tid]);
        }
        __syncthreads();
        int B2 = sB2;
        for (int it = 0; it < 16; ++it) {
            unsigned pack = binsw[it * 256 + tid];
            int a0 = it * 1024 + tid * 4;
#pragma unroll
            for (int q = 0; q < 4; ++q) {
                int b = (pack >> (q * 8)) & 255;
                if (b < B) { unsigned pp = atomicAdd(&s_cnt, 1u); s_list[pp] = a0 + q; }
                else if (b == B) {
                    int a = a0 + q;
                    float d2 = dist2(pos[a * 3], pos[a * 3 + 1], pos[a * 3 + 2], cx, cy, cz);
                    int k2 = (int)((d2 - lo2) * 655.36f);
                    if (k2 < 0) k2 = 0; if (k2 > 255) k2 = 255;
                    if (k2 < B2) { unsigned pp = atomicAdd(&s_cnt, 1u); s_list[pp] = a; }
                    else if (k2 == B2) {
                        unsigned c = atomicAdd(&s_ccnt, 1u);
                        if (c < 128u) candi[c] = a;
                    }
                }
            }
        }
    }
    __syncthreads();

    // ---- rank boundary candidates by exact (d, idx), take needN smallest
    int needN = (mode == 0) ? 0 : ((mode == 1) ? sNeed : sNeed2);
    unsigned C = s_ccnt; if (C > 128u) C = 128u;
    if (tid < (int)C) {
        int a = candi[tid];
        float d2 = dist2(pos[a * 3], pos[a * 3 + 1], pos[a * 3 + 2], cx, cy, cz);
        candd[tid] = sqrtf(d2 + 1e-12f);
    }
    __syncthreads();
    if (tid < (int)C) {
        float di = candd[tid]; int ii = candi[tid];
        int rank = 0;
        for (unsigned j = 0; j < C; ++j) {
            float dj = candd[j]; int ij = candi[j];
            if (dj < di || (dj == di && ij < ii)) ++rank;
        }
        if (rank < needN) { unsigned pp = atomicAdd(&s_cnt, 1u); s_list[pp] = ii; }
    }
    __syncthreads();
    if (tid < K_) nbr[r * K_ + tid] = (tid < (int)s_cnt) ? s_list[tid] : -1;
}

// ---------------------------------------------------------------- env: MFMA point-MLP + masked maxpool + env@W2
__global__ __launch_bounds__(256) void k_env(
    const float* __restrict__ pos, const int* __restrict__ atom_name,
    const int* __restrict__ ca_idx, const int* __restrict__ nbr,
    const float* __restrict__ emb, const float* __restrict__ Wxyz,
    const unsigned short* __restrict__ W1t,   // [128][64] bf16
    const float* __restrict__ b1,
    const float* __restrict__ W2, const float* __restrict__ b2,
    float* __restrict__ outZ1)
{
    __shared__ __align__(16) float pts[48 * 68];            // padded rows (272B)
    __shared__ __align__(16) unsigned short W1s[128 * 72];  // padded rows (144B)
    __shared__ float env128[128];
    __shared__ float sWxyz[192];
    __shared__ float s_d[48][3];
    __shared__ int s_a[48];
    __shared__ int s_an[48];

    int tid = threadIdx.x, r = blockIdx.x;

    // stage W1t into padded LDS rows
    for (int c = tid; c < 1024; c += 256)
        *(uint4*)((char*)W1s + (c >> 3) * 144 + (c & 7) * 16) = ((const uint4*)W1t)[c];
    if (tid < 192) sWxyz[tid] = Wxyz[tid];

    int ca = ca_idx[r];
    float cx = pos[ca * 3 + 0], cy = pos[ca * 3 + 1], cz = pos[ca * 3 + 2];
    if (tid < K_) {
        int a = nbr[r * K_ + tid];
        s_a[tid] = a;
        if (a >= 0) {
            s_d[tid][0] = pos[a * 3 + 0] - cx;
            s_d[tid][1] = pos[a * 3 + 1] - cy;
            s_d[tid][2] = pos[a * 3 + 2] - cz;
            s_an[tid] = atom_name[a];
        } else {
            s_d[tid][0] = 0.f; s_d[tid][1] = 0.f; s_d[tid][2] = 0.f;
            s_an[tid] = 0;
        }
    }
    __syncthreads();

    // build pts f32 [48][64] (padded)
    for (int idx = tid; idx < K_ * 64; idx += 256) {
        int row = idx >> 6, k = idx & 63;
        int a = s_a[row];
        float v = 0.f;
        if (a >= 0) {
            v = emb[s_an[row] * 64 + k]
              + s_d[row][0] * sWxyz[k] + s_d[row][1] * sWxyz[64 + k]
              + s_d[row][2] * sWxyz[128 + k];
        }
        pts[row * 68 + k] = v;
    }
    __syncthreads();

    // MFMA: wave w covers output cols 32w..32w+31 (n-tiles 2w, 2w+1), all 48 rows
    int w = tid >> 6, l = tid & 63;
    int fr = l & 15, fo = l >> 4;
    f32x4v acc[3][2];
#pragma unroll
    for (int m = 0; m < 3; ++m)
#pragma unroll
        for (int n = 0; n < 2; ++n) acc[m][n] = (f32x4v){0.f, 0.f, 0.f, 0.f};

#pragma unroll
    for (int ks = 0; ks < 2; ++ks) {
        bfrag8 af[3], bf[2];
#pragma unroll
        for (int m = 0; m < 3; ++m) {
            int row = 16 * m + fr;
            const char* base = (const char*)pts + row * 272 + ks * 128 + fo * 32;
            float4 v0 = *(const float4*)base;
            float4 v1 = *(const float4*)(base + 16);
            bfrag8 t;
            t[0] = (short)bf16rne(v0.x); t[1] = (short)bf16rne(v0.y);
            t[2] = (short)bf16rne(v0.z); t[3] = (short)bf16rne(v0.w);
            t[4] = (short)bf16rne(v1.x); t[5] = (short)bf16rne(v1.y);
            t[6] = (short)bf16rne(v1.z); t[7] = (short)bf16rne(v1.w);
            af[m] = t;
        }
#pragma unroll
        for (int n = 0; n < 2; ++n) {
            int wrow = (2 * w + n) * 16 + fr;
            bf[n] = *(const bfrag8*)((const char*)W1s + wrow * 144 + ks * 64 + fo * 16);
        }
#pragma unroll
        for (int m = 0; m < 3; ++m)
#pragma unroll
            for (int n = 0; n < 2; ++n)
                acc[m][n] = __builtin_amdgcn_mfma_f32_16x16x32_bf16(af[m], bf[n], acc[m][n], 0, 0, 0);
    }

    // bias + relu + masked maxpool (D: col=l&15, row=(l>>4)*4+i)
#pragma unroll
    for (int n = 0; n < 2; ++n) {
        int col = 32 * w + n * 16 + fr;
        float bv = b1[col];
        float m = -1e30f;
#pragma unroll
        for (int mt = 0; mt < 3; ++mt) {
#pragma unroll
            for (int i = 0; i < 4; ++i) {
                int row = 16 * mt + fo * 4 + i;
                if (s_a[row] >= 0) m = fmaxf(m, fmaxf(acc[mt][n][i] + bv, 0.f));
            }
        }
        m = fmaxf(m, __shfl_xor(m, 16));
        m = fmaxf(m, __shfl_xor(m, 32));
        if (fo == 0 && (l & 48) == 0) env128[col] = m;
    }
    __syncthreads();

    // env256 = relu(env128 @ W2 + b2)
    {
        float s = b2[tid];
        for (int i = 0; i < 128; ++i) s += env128[i] * W2[i * 256 + tid];
        outZ1[(size_t)r * 768 + 512 + tid] = fmaxf(s, 0.f);
    }
}

// ---------------------------------------------------------------- bf16 MFMA GEMM (+optional fused BN-input / column stats)
template<bool RELU_OUT, bool BN_A, bool STATS>
__global__ __launch_bounds__(256) void k_mgemm(
    const float* __restrict__ A, int lda, int K,
    const unsigned short* __restrict__ Bt,   // [512][K] bf16
    const float* __restrict__ bias,
    const float* __restrict__ stats, const float* __restrict__ gamma,
    const float* __restrict__ beta,
    float* __restrict__ C, int ldc, float* __restrict__ statsOut)
{
    __shared__ __align__(16) unsigned short As[32 * 32];
    __shared__ __align__(16) unsigned short Bs[64 * 32];
    __shared__ float bnsc[BN_A ? 512 : 1];
    __shared__ float bnsh[BN_A ? 512 : 1];

    int tid = threadIdx.x;
    int m0 = blockIdx.y * 32, n0 = blockIdx.x * 64;

    if (BN_A) {
        for (int i = tid; i < 512; i += 256) {
            float mean = stats[i] * (1.0f / 2048.0f);
            float var = stats[512 + i] * (1.0f / 2048.0f) - mean * mean;
            float inv = 1.0f / sqrtf(var + 1e-5f);
            float scv = gamma[i] * inv;
            bnsc[i] = scv;
            bnsh[i] = beta[i] - mean * scv;
        }
        __syncthreads();
    }

    int w = tid >> 6, l = tid & 63;
    int wm = w >> 1, wn = w & 1;

    int ar = tid >> 3, ac = tid & 7;
    int aslot = ac >> 1, ahalf = ac & 1;
    int abyte = ar * 64 + ((aslot ^ ((ar >> 1) & 3)) << 4) + ahalf * 8;
    int bn_ = tid >> 2, bs_ = tid & 3;
    int bbyte = bn_ * 64 + ((bs_ ^ ((bn_ >> 1) & 3)) << 4);

    int fr = l & 15, fo = l >> 4;
    int arow = 16 * wm + fr;
    int afbyte = arow * 64 + ((fo ^ ((arow >> 1) & 3)) << 4);
    int bcol0 = 32 * wn + fr;
    int bfbyte0 = bcol0 * 64 + ((fo ^ ((bcol0 >> 1) & 3)) << 4);
    int bcol1 = bcol0 + 16;
    int bfbyte1 = bcol1 * 64 + ((fo ^ ((bcol1 >> 1) & 3)) << 4);

    f32x4v acc0 = { 0.f, 0.f, 0.f, 0.f };
    f32x4v acc1 = { 0.f, 0.f, 0.f, 0.f };

    for (int k0 = 0; k0 < K; k0 += 32) {
        float4 av = *(const float4*)(A + (size_t)(m0 + ar) * lda + k0 + ac * 4);
        uint4 bv = *(const uint4*)(Bt + (size_t)(n0 + bn_) * K + k0 + bs_ * 8);
        if (BN_A) {
            int kb = k0 + ac * 4;
            av.x = fmaxf(av.x * bnsc[kb + 0] + bnsh[kb + 0], 0.f);
            av.y = fmaxf(av.y * bnsc[kb + 1] + bnsh[kb + 1], 0.f);
            av.z = fmaxf(av.z * bnsc[kb + 2] + bnsh[kb + 2], 0.f);
            av.w = fmaxf(av.w * bnsc[kb + 3] + bnsh[kb + 3], 0.f);
        }
        unsigned lo = (unsigned)bf16rne(av.x) | ((unsigned)bf16rne(av.y) << 16);
        unsigned hi = (unsigned)bf16rne(av.z) | ((unsigned)bf16rne(av.w) << 16);
        __syncthreads();
        *(uint2*)((char*)As + abyte) = make_uint2(lo, hi);
        *(uint4*)((char*)Bs + bbyte) = bv;
        __syncthreads();

        bfrag8 af = *(const bfrag8*)((const char*)As + afbyte);
        bfrag8 bf0 = *(const bfrag8*)((const char*)Bs + bfbyte0);
        bfrag8 bf1 = *(const bfrag8*)((const char*)Bs + bfbyte1);
        acc0 = __builtin_amdgcn_mfma_f32_16x16x32_bf16(af, bf0, acc0, 0, 0, 0);
        acc1 = __builtin_amdgcn_mfma_f32_16x16x32_bf16(af, bf1, acc1, 0, 0, 0);
    }

    int col0 = n0 + 32 * wn + fr;
    int row = m0 + 16 * wm + fo * 4;
    float bb0 = bias[col0], bb1 = bias[col0 + 16];
    float s0 = 0.f, q0 = 0.f, s1 = 0.f, q1 = 0.f;
#pragma unroll
    for (int i = 0; i < 4; ++i) {
        float v0 = acc0[i] + bb0;
        float v1 = acc1[i] + bb1;
        if (RELU_OUT) { v0 = fmaxf(v0, 0.f); v1 = fmaxf(v1, 0.f); }
        if (STATS) { s0 += v0; q0 += v0 * v0; s1 += v1; q1 += v1 * v1; }
        C[(size_t)(row + i) * ldc + col0] = v0;
        C[(size_t)(row + i) * ldc + col0 + 16] = v1;
    }
    if (STATS) {
        s0 += __shfl_xor(s0, 16); s0 += __shfl_xor(s0, 32);
        q0 += __shfl_xor(q0, 16); q0 += __shfl_xor(q0, 32);
        s1 += __shfl_xor(s1, 16); s1 += __shfl_xor(s1, 32);
        q1 += __shfl_xor(q1, 16); q1 += __shfl_xor(q1, 32);
        if (fo == 0 && (l & 48) == 0) {
            atomicAdd(&statsOut[col0], s0);
            atomicAdd(&statsOut[512 + col0], q0);
            atomicAdd(&statsOut[col0 + 16], s1);
            atomicAdd(&statsOut[512 + col0 + 16], q1);
        }
    }
}

// ---------------------------------------------------------------- launch
extern "C" void kernel_launch(void* const* d_in, const int* in_sizes, int n_in,
                              void* d_out, int out_size, void* d_ws, size_t ws_size,
                              hipStream_t stream)
{
    const float* node   = (const float*)d_in[0];
    const float* pos    = (const float*)d_in[1];
    const int*   aname  = (const int*)d_in[2];
    const int*   caidx  = (const int*)d_in[3];
    const int*   esrc   = (const int*)d_in[4];
    const int*   edst   = (const int*)d_in[5];
    const int*   erel   = (const int*)d_in[6];
    const float* emb    = (const float*)d_in[7];
    const float* Wres   = (const float*)d_in[8];
    const float* bres   = (const float*)d_in[9];
    const float* Wxyz   = (const float*)d_in[10];
    const float* W1     = (const float*)d_in[11];
    const float* b1     = (const float*)d_in[12];
    const float* W2     = (const float*)d_in[13];
    const float* b2     = (const float*)d_in[14];
    const float* Wconv  = (const float*)d_in[15];
    const float* bconv  = (const float*)d_in[16];
    const float* Wself  = (const float*)d_in[17];
    const float* We1    = (const float*)d_in[18];
    const float* be1    = (const float*)d_in[19];
    const float* gamma1 = (const float*)d_in[20];
    const float* beta1  = (const float*)d_in[21];
    const float* We2    = (const float*)d_in[22];
    const float* be2    = (const float*)d_in[23];
    float* out = (float*)d_out;

    char* ws = (char*)d_ws;
    float* resfeat = (float*)(ws + 0);                    // R*64 f32
    float* bufA    = (float*)(ws + 524288);               // R*512 f32 agg|rf
    float* bufZ1   = (float*)(ws + 4718592);              // R*768 f32 hres|env
    float* bufZ2   = (float*)(ws + 11010048);             // R*512 f32 z
    int*   nbr     = (int*)  (ws + 15204352);             // R*48 int
    float* stats   = (float*)(ws + 15597568);             // 1024 f32
    unsigned short* Bt1 = (unsigned short*)(ws + 15601664); // 512x512 bf16
    unsigned short* Bt2 = (unsigned short*)(ws + 16125952); // 512x768 bf16
    unsigned short* Bt3 = (unsigned short*)(ws + 16912384); // 512x512 bf16
    unsigned short* W1t = (unsigned short*)(ws + 17436672); // 128x64 bf16
    int* cnt    = (int*)(ws + 17453056);                  // 14336
    int* offs   = (int*)(ws + 17510400);                  // 14337
    int* cursor = (int*)(ws + 17567760);                  // 14336
    int* eord   = (int*)(ws + 17625120);                  // E ints

    hipMemsetAsync(cnt, 0, 14336 * 4, stream);
    hipMemsetAsync(stats, 0, 1024 * 4, stream);

    // edge CSR build
    k_hist<<<E_ / 256, 256, 0, stream>>>(edst, erel, cnt);
    k_scan<<<1, 1024, 0, stream>>>(cnt, offs, cursor);
    k_scatter<<<E_ / 256, 256, 0, stream>>>(esrc, edst, erel, cursor, eord);

    k_prep<<<4128, 256, 0, stream>>>(Wconv, Wself, We1, We2, W1, node, Wres, bres,
                                     Bt1, Bt2, Bt3, W1t, resfeat, bufA);
    k_ball<<<R_, 256, 0, stream>>>(pos, caidx, nbr);
    k_env<<<R_, 256, 0, stream>>>(pos, aname, caidx, nbr, emb, Wxyz, W1t, b1, W2, b2, bufZ1);
    k_gather<<<R_, 256, 0, stream>>>(offs, eord, resfeat, bufA);

    dim3 gg(512 / 64, R_ / 32);
    // hres = relu([agg|rf] @ [Wconv;Wself] + bconv) -> bufZ1 cols 0..511
    k_mgemm<true, false, false><<<gg, 256, 0, stream>>>(
        bufA, 512, 512, Bt1, bconv, nullptr, nullptr, nullptr, bufZ1, 768, nullptr);
    // z = [hres|env] @ We1 + be1 -> bufZ2  (+ fused BN column stats)
    k_mgemm<false, false, true><<<gg, 256, 0, stream>>>(
        bufZ1, 768, 768, Bt2, be1, nullptr, nullptr, nullptr, bufZ2, 512, stats);
    // out = relu(BN(z)) @ We2 + be2
    k_mgemm<false, true, false><<<gg, 256, 0, stream>>>(
        bufZ2, 512, 512, Bt3, be2, stats, gamma1, beta1, out, 512, nullptr);
}

// Round 8
// 232.012 us; speedup vs baseline: 1.0247x; 1.0247x over previous
//
#include <hip/hip_runtime.h>
#include <math.h>

#define R_ 2048
#define A_ 16384
#define E_ 131072
#define K_ 48
#define NREL_ 7

typedef __attribute__((ext_vector_type(8))) short bfrag8;
typedef __attribute__((ext_vector_type(4))) float f32x4v;

__device__ __forceinline__ unsigned short bf16rne(float f) {
    unsigned u = __builtin_bit_cast(unsigned, f);
    u += 0x7FFFu + ((u >> 16) & 1u);
    return (unsigned short)(u >> 16);
}

__device__ __forceinline__ float dist2(float x, float y, float z,
                                       float cx, float cy, float cz) {
    float dx = x - cx, dy = y - cy, dz = z - cz;
    return fmaf(dx, dx, fmaf(dy, dy, dz * dz));   // deterministic everywhere
}

// ---------------------------------------------------------------- prep: weights->bf16 + res_feat + buffer zeroing
__global__ __launch_bounds__(256) void k_prep(
    const float* __restrict__ Wconv, const float* __restrict__ Wself,
    const float* __restrict__ We1, const float* __restrict__ We2,
    const float* __restrict__ W1,
    const float* __restrict__ node, const float* __restrict__ Wres,
    const float* __restrict__ bres,
    unsigned short* __restrict__ Bt1, unsigned short* __restrict__ Bt2,
    unsigned short* __restrict__ Bt3, unsigned short* __restrict__ W1t,
    float* __restrict__ resfeat, float* __restrict__ bufA,
    float* __restrict__ stats)
{
    int id = blockIdx.x * 256 + threadIdx.x;
    if (id < 262144) {
        int k = id & 511, n = id >> 9;
        float v = (k < 448) ? Wconv[k * 512 + n] : Wself[(k - 448) * 512 + n];
        Bt1[n * 512 + k] = bf16rne(v);
    } else if (id < 655360) {
        int rel = id - 262144;
        int k = rel % 768, n = rel / 768;
        Bt2[n * 768 + k] = bf16rne(We1[k * 512 + n]);
    } else if (id < 917504) {
        int rel = id - 655360;
        int k = rel & 511, n = rel >> 9;
        Bt3[n * 512 + k] = bf16rne(We2[k * 512 + n]);
    } else if (id < 925696) {
        int rel = id - 917504;
        int k = rel & 63, n = rel >> 6;     // n<128, k<64
        W1t[n * 64 + k] = bf16rne(W1[k * 128 + n]);
    } else if (id < 1056768) {
        int rel = id - 925696;
        int r = rel >> 6, c = rel & 63;
        float s = bres[c];
#pragma unroll
        for (int i = 0; i < 21; ++i) s += node[r * 21 + i] * Wres[i * 64 + c];
        resfeat[r * 64 + c] = s;
        bufA[(size_t)r * 512 + 448 + c] = s;
    } else if (id < 1974272) {
        int rel = id - 1056768;             // zero agg region: R x 448
        int r = rel / 448, c = rel % 448;
        bufA[(size_t)r * 512 + c] = 0.f;
    } else if (id < 1975296) {
        stats[id - 1974272] = 0.f;
    }
}

// ---------------------------------------------------------------- edge scatter (atomic; proven round-6)
__global__ __launch_bounds__(256) void k_edges(
    const int* __restrict__ esrc, const int* __restrict__ edst,
    const int* __restrict__ erel, const float* __restrict__ resfeat,
    float* __restrict__ bufA)
{
    int idx = blockIdx.x * 256 + threadIdx.x;
    int e = idx >> 6, c = idx & 63;
    int d = edst[e], rel = erel[e], s = esrc[e];
    atomicAdd(&bufA[(size_t)d * 512 + rel * 64 + c], resfeat[s * 64 + c]);
}

// ---------------------------------------------------------------- fused ball query + env (point-MLP MFMA + maxpool + W2)
__global__ __launch_bounds__(256) void k_ball_env(
    const float* __restrict__ pos, const int* __restrict__ ca_idx,
    const int* __restrict__ atom_name,
    const float* __restrict__ emb, const float* __restrict__ Wxyz,
    const unsigned short* __restrict__ W1t,   // [128][64] bf16
    const float* __restrict__ b1,
    const float* __restrict__ W2, const float* __restrict__ b2,
    float* __restrict__ outZ1)
{
    // union buffer: ball phase (<=20.5KB) then env phase (<=33.8KB)
    __shared__ __align__(16) char SB[33792];
    __shared__ int s_list[64];
    __shared__ unsigned s_cnt, s_ccnt;
    __shared__ int sB, sNeed, sB2, sNeed2, sTotal;

    // ball-phase aliases
    unsigned* binsw = (unsigned*)SB;                 // 4096 u32, 16384B
    unsigned* hist  = (unsigned*)(SB + 16384);       // 256
    unsigned* hist2 = (unsigned*)(SB + 17408);       // 256
    int*      sc    = (int*)(SB + 18432);            // 256
    float*    candd = (float*)(SB + 19456);          // 128
    int*      candi = (int*)(SB + 19968);            // 128 -> 20480

    // env-phase aliases (overwrite ball region after barrier)
    float*          pts    = (float*)SB;                      // 48*68 f = 13056B
    unsigned short* W1s    = (unsigned short*)(SB + 13056);   // 128*72 bf16 = 18432B -> 31488
    float*          sWxyz  = (float*)(SB + 31488);            // 192 f -> 32256
    float*          s_dv   = (float*)(SB + 32256);            // 48*3 f -> 32832
    float*          env128 = (float*)(SB + 32832);            // 128 f -> 33344
    int*            s_an   = (int*)(SB + 33344);              // 48 -> 33536
    int*            s_aa   = (int*)(SB + 33536);              // 48 -> 33728

    int tid = threadIdx.x;
    int r = blockIdx.x;
    int ca = ca_idx[r];
    float cx = pos[ca * 3 + 0], cy = pos[ca * 3 + 1], cz = pos[ca * 3 + 2];

    hist[tid] = 0u;
    if (tid == 0) { s_cnt = 0u; s_ccnt = 0u; }
    __syncthreads();

    // ---- ball pass 1: d2, bin byte -> LDS, histogram
    for (int it = 0; it < 16; ++it) {
        int a0 = it * 1024 + tid * 4;
        const float4* p = (const float4*)(pos + (size_t)a0 * 3);
        float4 p0 = p[0], p1 = p[1], p2 = p[2];
        float xs[4] = { p0.x, p0.w, p1.z, p2.y };
        float ys[4] = { p0.y, p1.x, p1.w, p2.z };
        float zs[4] = { p0.z, p1.y, p2.x, p2.w };
        unsigned pack = 0;
#pragma unroll
        for (int q = 0; q < 4; ++q) {
            float d2 = dist2(xs[q], ys[q], zs[q], cx, cy, cz);
            int b = 255;
            if (d2 < 100.0f) {
                b = (int)(d2 * 2.56f); if (b > 254) b = 254;
                atomicAdd(&hist[b], 1u);
            }
            pack |= (unsigned)b << (q * 8);
        }
        binsw[it * 256 + tid] = pack;
    }
    __syncthreads();

    // ---- scan
    sc[tid] = (int)hist[tid];
    __syncthreads();
    for (int s = 1; s < 256; s <<= 1) {
        int v = (tid >= s) ? sc[tid - s] : 0;
        __syncthreads();
        sc[tid] += v;
        __syncthreads();
    }
    if (tid == 0) sTotal = sc[255];
    if (sc[tid] >= K_ && (tid == 0 || sc[tid - 1] < K_)) {
        sB = tid;
        sNeed = K_ - (sc[tid] - (int)hist[tid]);
    }
    __syncthreads();

    int mode = (sTotal <= K_) ? 0 : (((int)hist[sB] > 128) ? 2 : 1);

    if (mode <= 1) {
        int B = (mode == 0) ? 255 : sB;
        for (int it = 0; it < 16; ++it) {
            unsigned pack = binsw[it * 256 + tid];
            int a0 = it * 1024 + tid * 4;
#pragma unroll
            for (int q = 0; q < 4; ++q) {
                int b = (pack >> (q * 8)) & 255;
                if (b < B) { unsigned pp = atomicAdd(&s_cnt, 1u); s_list[pp] = a0 + q; }
                else if (b == B && mode == 1) {
                    unsigned c = atomicAdd(&s_ccnt, 1u);
                    if (c < 128u) candi[c] = a0 + q;
                }
            }
        }
    } else {
        int B = sB;
        float lo2 = B * 0.390625f;
        hist2[tid] = 0u;
        __syncthreads();
        for (int it = 0; it < 16; ++it) {
            unsigned pack = binsw[it * 256 + tid];
            int a0 = it * 1024 + tid * 4;
#pragma unroll
            for (int q = 0; q < 4; ++q) {
                if (((pack >> (q * 8)) & 255) == (unsigned)B) {
                    int a = a0 + q;
                    float d2 = dist2(pos[a * 3], pos[a * 3 + 1], pos[a * 3 + 2], cx, cy, cz);
                    int k2 = (int)((d2 - lo2) * 655.36f);
                    if (k2 < 0) k2 = 0; if (k2 > 255) k2 = 255;
                    atomicAdd(&hist2[k2], 1u);
                }
            }
        }
        __syncthreads();
        sc[tid] = (int)hist2[tid];
        __syncthreads();
        for (int s = 1; s < 256; s <<= 1) {
            int v = (tid >= s) ? sc[tid - s] : 0;
            __syncthreads();
            sc[tid] += v;
            __syncthreads();
        }
        if (sc[tid] >= sNeed && (tid == 0 || sc[tid - 1] < sNeed)) {
            sB2 = tid;
            sNeed2 = sNeed - (sc[tid] - (int)hist2[tid]);
        }
        __syncthreads();
        int B2 = sB2;
        for (int it = 0; it < 16; ++it) {
            unsigned pack = binsw[it * 256 + tid];
            int a0 = it * 1024 + tid * 4;
#pragma unroll
            for (int q = 0; q < 4; ++q) {
                int b = (pack >> (q * 8)) & 255;
                if (b < B) { unsigned pp = atomicAdd(&s_cnt, 1u); s_list[pp] = a0 + q; }
                else if (b == B) {
                    int a = a0 + q;
                    float d2 = dist2(pos[a * 3], pos[a * 3 + 1], pos[a * 3 + 2], cx, cy, cz);
                    int k2 = (int)((d2 - lo2) * 655.36f);
                    if (k2 < 0) k2 = 0; if (k2 > 255) k2 = 255;
                    if (k2 < B2) { unsigned pp = atomicAdd(&s_cnt, 1u); s_list[pp] = a; }
                    else if (k2 == B2) {
                        unsigned c = atomicAdd(&s_ccnt, 1u);
                        if (c < 128u) candi[c] = a;
                    }
                }
            }
        }
    }
    __syncthreads();

    // ---- rank boundary candidates by exact (d, idx)
    int needN = (mode == 0) ? 0 : ((mode == 1) ? sNeed : sNeed2);
    unsigned C = s_ccnt; if (C > 128u) C = 128u;
    if (tid < (int)C) {
        int a = candi[tid];
        float d2 = dist2(pos[a * 3], pos[a * 3 + 1], pos[a * 3 + 2], cx, cy, cz);
        candd[tid] = sqrtf(d2 + 1e-12f);
    }
    __syncthreads();
    if (tid < (int)C) {
        float di = candd[tid]; int ii = candi[tid];
        int rank = 0;
        for (unsigned j = 0; j < C; ++j) {
            float dj = candd[j]; int ij = candi[j];
            if (dj < di || (dj == di && ij < ii)) ++rank;
        }
        if (rank < needN) { unsigned pp = atomicAdd(&s_cnt, 1u); s_list[pp] = ii; }
    }
    __syncthreads();   // ball phase done: s_list/s_cnt final; SB free for env

    // ================= env phase =================
    unsigned nb = s_cnt;

    // stage W1t into padded LDS rows (overwrites ball bins)
    for (int c = tid; c < 1024; c += 256)
        *(uint4*)((char*)W1s + (c >> 3) * 144 + (c & 7) * 16) = ((const uint4*)W1t)[c];
    if (tid < 192) sWxyz[tid] = Wxyz[tid];
    if (tid < K_) {
        int a = (tid < (int)nb) ? s_list[tid] : -1;
        s_aa[tid] = a;
        if (a >= 0) {
            s_dv[tid * 3 + 0] = pos[a * 3 + 0] - cx;
            s_dv[tid * 3 + 1] = pos[a * 3 + 1] - cy;
            s_dv[tid * 3 + 2] = pos[a * 3 + 2] - cz;
            s_an[tid] = atom_name[a];
        } else {
            s_dv[tid * 3 + 0] = 0.f; s_dv[tid * 3 + 1] = 0.f; s_dv[tid * 3 + 2] = 0.f;
            s_an[tid] = 0;
        }
    }
    __syncthreads();

    // build pts f32 [48][64] (padded to 68)
    for (int idx = tid; idx < K_ * 64; idx += 256) {
        int row = idx >> 6, k = idx & 63;
        int a = s_aa[row];
        float v = 0.f;
        if (a >= 0) {
            v = emb[s_an[row] * 64 + k]
              + s_dv[row * 3 + 0] * sWxyz[k] + s_dv[row * 3 + 1] * sWxyz[64 + k]
              + s_dv[row * 3 + 2] * sWxyz[128 + k];
        }
        pts[row * 68 + k] = v;
    }
    __syncthreads();

    // MFMA: wave w covers output cols 32w..32w+31
    int w = tid >> 6, l = tid & 63;
    int fr = l & 15, fo = l >> 4;
    f32x4v acc[3][2];
#pragma unroll
    for (int m = 0; m < 3; ++m)
#pragma unroll
        for (int n = 0; n < 2; ++n) acc[m][n] = (f32x4v){0.f, 0.f, 0.f, 0.f};

#pragma unroll
    for (int ks = 0; ks < 2; ++ks) {
        bfrag8 af[3], bf[2];
#pragma unroll
        for (int m = 0; m < 3; ++m) {
            int row = 16 * m + fr;
            const char* base = (const char*)pts + row * 272 + ks * 128 + fo * 32;
            float4 v0 = *(const float4*)base;
            float4 v1 = *(const float4*)(base + 16);
            bfrag8 t;
            t[0] = (short)bf16rne(v0.x); t[1] = (short)bf16rne(v0.y);
            t[2] = (short)bf16rne(v0.z); t[3] = (short)bf16rne(v0.w);
            t[4] = (short)bf16rne(v1.x); t[5] = (short)bf16rne(v1.y);
            t[6] = (short)bf16rne(v1.z); t[7] = (short)bf16rne(v1.w);
            af[m] = t;
        }
#pragma unroll
        for (int n = 0; n < 2; ++n) {
            int wrow = (2 * w + n) * 16 + fr;
            bf[n] = *(const bfrag8*)((const char*)W1s + wrow * 144 + ks * 64 + fo * 16);
        }
#pragma unroll
        for (int m = 0; m < 3; ++m)
#pragma unroll
            for (int n = 0; n < 2; ++n)
                acc[m][n] = __builtin_amdgcn_mfma_f32_16x16x32_bf16(af[m], bf[n], acc[m][n], 0, 0, 0);
    }

    // bias + relu + masked maxpool
#pragma unroll
    for (int n = 0; n < 2; ++n) {
        int col = 32 * w + n * 16 + fr;
        float bv = b1[col];
        float m = -1e30f;
#pragma unroll
        for (int mt = 0; mt < 3; ++mt) {
#pragma unroll
            for (int i = 0; i < 4; ++i) {
                int row = 16 * mt + fo * 4 + i;
                if (s_aa[row] >= 0) m = fmaxf(m, fmaxf(acc[mt][n][i] + bv, 0.f));
            }
        }
        m = fmaxf(m, __shfl_xor(m, 16));
        m = fmaxf(m, __shfl_xor(m, 32));
        if (fo == 0 && (l & 48) == 0) env128[col] = m;
    }
    __syncthreads();

    // env256 = relu(env128 @ W2 + b2)
    {
        float s = b2[tid];
        for (int i = 0; i < 128; ++i) s += env128[i] * W2[i * 256 + tid];
        outZ1[(size_t)r * 768 + 512 + tid] = fmaxf(s, 0.f);
    }
}

// ---------------------------------------------------------------- bf16 MFMA GEMM, BM=64/BN=64/BK=32 (+BN-input / stats)
template<bool RELU_OUT, bool BN_A, bool STATS>
__global__ __launch_bounds__(256) void k_mgemm(
    const float* __restrict__ A, int lda, int K,
    const unsigned short* __restrict__ Bt,   // [512][K] bf16
    const float* __restrict__ bias,
    const float* __restrict__ stats, const float* __restrict__ gamma,
    const float* __restrict__ beta,
    float* __restrict__ C, int ldc, float* __restrict__ statsOut)
{
    __shared__ __align__(16) unsigned short As[64 * 32];
    __shared__ __align__(16) unsigned short Bs[64 * 32];
    __shared__ float bnsc[BN_A ? 512 : 1];
    __shared__ float bnsh[BN_A ? 512 : 1];

    int tid = threadIdx.x;
    int m0 = blockIdx.y * 64, n0 = blockIdx.x * 64;

    if (BN_A) {
        for (int i = tid; i < 512; i += 256) {
            float mean = stats[i] * (1.0f / 2048.0f);
            float var = stats[512 + i] * (1.0f / 2048.0f) - mean * mean;
            float inv = 1.0f / sqrtf(var + 1e-5f);
            float scv = gamma[i] * inv;
            bnsc[i] = scv;
            bnsh[i] = beta[i] - mean * scv;
        }
        __syncthreads();
    }

    int w = tid >> 6, l = tid & 63;
    int wm = w >> 1, wn = w & 1;

    // staging: A row=tid>>2 (0..63), 8 cols at (tid&3)*8; B col=tid>>2, 8 k at (tid&3)*8
    int ar = tid >> 2, aslot = tid & 3, acg = aslot * 8;
    int abyte = ar * 64 + ((aslot ^ ((ar >> 1) & 3)) << 4);
    int bn_ = tid >> 2, bslot = tid & 3;
    int bbyte = bn_ * 64 + ((bslot ^ ((bn_ >> 1) & 3)) << 4);

    int fr = l & 15, fo = l >> 4;
    int ar0 = 32 * wm + fr, ar1 = ar0 + 16;
    int af0 = ar0 * 64 + ((fo ^ ((ar0 >> 1) & 3)) << 4);
    int af1 = ar1 * 64 + ((fo ^ ((ar1 >> 1) & 3)) << 4);
    int bc0 = 32 * wn + fr, bc1 = bc0 + 16;
    int bf0o = bc0 * 64 + ((fo ^ ((bc0 >> 1) & 3)) << 4);
    int bf1o = bc1 * 64 + ((fo ^ ((bc1 >> 1) & 3)) << 4);

    f32x4v acc00 = {0.f,0.f,0.f,0.f}, acc01 = {0.f,0.f,0.f,0.f};
    f32x4v acc10 = {0.f,0.f,0.f,0.f}, acc11 = {0.f,0.f,0.f,0.f};

    for (int k0 = 0; k0 < K; k0 += 32) {
        const float* ap = A + (size_t)(m0 + ar) * lda + k0 + acg;
        float4 v0 = *(const float4*)ap;
        float4 v1 = *(const float4*)(ap + 4);
        uint4 bv = *(const uint4*)(Bt + (size_t)(n0 + bn_) * K + k0 + bslot * 8);
        if (BN_A) {
            int kb = k0 + acg;
            v0.x = fmaxf(v0.x * bnsc[kb + 0] + bnsh[kb + 0], 0.f);
            v0.y = fmaxf(v0.y * bnsc[kb + 1] + bnsh[kb + 1], 0.f);
            v0.z = fmaxf(v0.z * bnsc[kb + 2] + bnsh[kb + 2], 0.f);
            v0.w = fmaxf(v0.w * bnsc[kb + 3] + bnsh[kb + 3], 0.f);
            v1.x = fmaxf(v1.x * bnsc[kb + 4] + bnsh[kb + 4], 0.f);
            v1.y = fmaxf(v1.y * bnsc[kb + 5] + bnsh[kb + 5], 0.f);
            v1.z = fmaxf(v1.z * bnsc[kb + 6] + bnsh[kb + 6], 0.f);
            v1.w = fmaxf(v1.w * bnsc[kb + 7] + bnsh[kb + 7], 0.f);
        }
        uint4 aw;
        aw.x = (unsigned)bf16rne(v0.x) | ((unsigned)bf16rne(v0.y) << 16);
        aw.y = (unsigned)bf16rne(v0.z) | ((unsigned)bf16rne(v0.w) << 16);
        aw.z = (unsigned)bf16rne(v1.x) | ((unsigned)bf16rne(v1.y) << 16);
        aw.w = (unsigned)bf16rne(v1.z) | ((unsigned)bf16rne(v1.w) << 16);
        __syncthreads();   // previous iteration's frag reads done
        *(uint4*)((char*)As + abyte) = aw;
        *(uint4*)((char*)Bs + bbyte) = bv;
        __syncthreads();

        bfrag8 a0 = *(const bfrag8*)((const char*)As + af0);
        bfrag8 a1 = *(const bfrag8*)((const char*)As + af1);
        bfrag8 b0 = *(const bfrag8*)((const char*)Bs + bf0o);
        bfrag8 b1f = *(const bfrag8*)((const char*)Bs + bf1o);
        acc00 = __builtin_amdgcn_mfma_f32_16x16x32_bf16(a0, b0, acc00, 0, 0, 0);
        acc01 = __builtin_amdgcn_mfma_f32_16x16x32_bf16(a0, b1f, acc01, 0, 0, 0);
        acc10 = __builtin_amdgcn_mfma_f32_16x16x32_bf16(a1, b0, acc10, 0, 0, 0);
        acc11 = __builtin_amdgcn_mfma_f32_16x16x32_bf16(a1, b1f, acc11, 0, 0, 0);
    }

    // epilogue: D col=lane&15, row=(lane>>4)*4+i
    int col0 = n0 + 32 * wn + fr;
    int row0 = m0 + 32 * wm + fo * 4;
    float bb0 = bias[col0], bb1 = bias[col0 + 16];
    float s0 = 0.f, q0 = 0.f, s1 = 0.f, q1 = 0.f;
#pragma unroll
    for (int i = 0; i < 4; ++i) {
        float u00 = acc00[i] + bb0, u01 = acc01[i] + bb1;
        float u10 = acc10[i] + bb0, u11 = acc11[i] + bb1;
        if (RELU_OUT) {
            u00 = fmaxf(u00, 0.f); u01 = fmaxf(u01, 0.f);
            u10 = fmaxf(u10, 0.f); u11 = fmaxf(u11, 0.f);
        }
        if (STATS) {
            s0 += u00 + u10; q0 += u00 * u00 + u10 * u10;
            s1 += u01 + u11; q1 += u01 * u01 + u11 * u11;
        }
        C[(size_t)(row0 + i) * ldc + col0] = u00;
        C[(size_t)(row0 + i) * ldc + col0 + 16] = u01;
        C[(size_t)(row0 + 16 + i) * ldc + col0] = u10;
        C[(size_t)(row0 + 16 + i) * ldc + col0 + 16] = u11;
    }
    if (STATS) {
        s0 += __shfl_xor(s0, 16); s0 += __shfl_xor(s0, 32);
        q0 += __shfl_xor(q0, 16); q0 += __shfl_xor(q0, 32);
        s1 += __shfl_xor(s1, 16); s1 += __shfl_xor(s1, 32);
        q1 += __shfl_xor(q1, 16); q1 += __shfl_xor(q1, 32);
        if (fo == 0) {
            atomicAdd(&statsOut[col0], s0);
            atomicAdd(&statsOut[512 + col0], q0);
            atomicAdd(&statsOut[col0 + 16], s1);
            atomicAdd(&statsOut[512 + col0 + 16], q1);
        }
    }
}

// ---------------------------------------------------------------- launch
extern "C" void kernel_launch(void* const* d_in, const int* in_sizes, int n_in,
                              void* d_out, int out_size, void* d_ws, size_t ws_size,
                              hipStream_t stream)
{
    const float* node   = (const float*)d_in[0];
    const float* pos    = (const float*)d_in[1];
    const int*   aname  = (const int*)d_in[2];
    const int*   caidx  = (const int*)d_in[3];
    const int*   esrc   = (const int*)d_in[4];
    const int*   edst   = (const int*)d_in[5];
    const int*   erel   = (const int*)d_in[6];
    const float* emb    = (const float*)d_in[7];
    const float* Wres   = (const float*)d_in[8];
    const float* bres   = (const float*)d_in[9];
    const float* Wxyz   = (const float*)d_in[10];
    const float* W1     = (const float*)d_in[11];
    const float* b1     = (const float*)d_in[12];
    const float* W2     = (const float*)d_in[13];
    const float* b2     = (const float*)d_in[14];
    const float* Wconv  = (const float*)d_in[15];
    const float* bconv  = (const float*)d_in[16];
    const float* Wself  = (const float*)d_in[17];
    const float* We1    = (const float*)d_in[18];
    const float* be1    = (const float*)d_in[19];
    const float* gamma1 = (const float*)d_in[20];
    const float* beta1  = (const float*)d_in[21];
    const float* We2    = (const float*)d_in[22];
    const float* be2    = (const float*)d_in[23];
    float* out = (float*)d_out;

    char* ws = (char*)d_ws;
    float* resfeat = (float*)(ws + 0);                       // R*64 f32 (512KB)
    float* bufA    = (float*)(ws + 524288);                  // R*512 f32 (4MB)
    float* bufZ1   = (float*)(ws + 4718592);                 // R*768 f32 (6MB)
    float* bufZ2   = (float*)(ws + 11010048);                // R*512 f32 (4MB)
    float* stats   = (float*)(ws + 15204352);                // 1024 f32
    unsigned short* Bt1 = (unsigned short*)(ws + 15208448);  // 512x512 bf16
    unsigned short* Bt2 = (unsigned short*)(ws + 15732736);  // 512x768 bf16
    unsigned short* Bt3 = (unsigned short*)(ws + 16519168);  // 512x512 bf16
    unsigned short* W1t = (unsigned short*)(ws + 17043456);  // 128x64 bf16

    // prep: weights->bf16, res_feat, and zeroing of bufA-agg + stats (no memsets)
    k_prep<<<7716, 256, 0, stream>>>(Wconv, Wself, We1, We2, W1, node, Wres, bres,
                                     Bt1, Bt2, Bt3, W1t, resfeat, bufA, stats);
    k_ball_env<<<R_, 256, 0, stream>>>(pos, caidx, aname, emb, Wxyz, W1t, b1, W2, b2, bufZ1);
    k_edges<<<(size_t)E_ * 64 / 256, 256, 0, stream>>>(esrc, edst, erel, resfeat, bufA);

    dim3 gg(512 / 64, R_ / 64);
    // hres = relu([agg|rf] @ [Wconv;Wself] + bconv) -> bufZ1 cols 0..511
    k_mgemm<true, false, false><<<gg, 256, 0, stream>>>(
        bufA, 512, 512, Bt1, bconv, nullptr, nullptr, nullptr, bufZ1, 768, nullptr);
    // z = [hres|env] @ We1 + be1 -> bufZ2  (+ fused BN column stats)
    k_mgemm<false, false, true><<<gg, 256, 0, stream>>>(
        bufZ1, 768, 768, Bt2, be1, nullptr, nullptr, nullptr, bufZ2, 512, stats);
    // out = relu(BN(z)) @ We2 + be2
    k_mgemm<false, true, false><<<gg, 256, 0, stream>>>(
        bufZ2, 512, 512, Bt3, be2, stats, gamma1, beta1, out, 512, nullptr);
}

// Round 9
// 226.659 us; speedup vs baseline: 1.0489x; 1.0236x over previous
//
#include <hip/hip_runtime.h>
#include <math.h>

#define R_ 2048
#define A_ 16384
#define E_ 131072
#define K_ 48
#define NREL_ 7

typedef __attribute__((ext_vector_type(8))) short bfrag8;
typedef __attribute__((ext_vector_type(4))) float f32x4v;

__device__ __forceinline__ unsigned short bf16rne(float f) {
    unsigned u = __builtin_bit_cast(unsigned, f);
    u += 0x7FFFu + ((u >> 16) & 1u);
    return (unsigned short)(u >> 16);
}

__device__ __forceinline__ float dist2(float x, float y, float z,
                                       float cx, float cy, float cz) {
    float dx = x - cx, dy = y - cy, dz = z - cz;
    return fmaf(dx, dx, fmaf(dy, dy, dz * dz));   // deterministic everywhere
}

// ---------------------------------------------------------------- prep: weights->bf16 + res_feat + buffer zeroing
__global__ __launch_bounds__(256) void k_prep(
    const float* __restrict__ Wconv, const float* __restrict__ Wself,
    const float* __restrict__ We1, const float* __restrict__ We2,
    const float* __restrict__ W1,
    const float* __restrict__ node, const float* __restrict__ Wres,
    const float* __restrict__ bres,
    unsigned short* __restrict__ Bt1, unsigned short* __restrict__ Bt2,
    unsigned short* __restrict__ Bt3, unsigned short* __restrict__ W1t,
    float* __restrict__ resfeat, float* __restrict__ bufA,
    float* __restrict__ stats)
{
    int id = blockIdx.x * 256 + threadIdx.x;
    if (id < 262144) {
        int k = id & 511, n = id >> 9;
        float v = (k < 448) ? Wconv[k * 512 + n] : Wself[(k - 448) * 512 + n];
        Bt1[n * 512 + k] = bf16rne(v);
    } else if (id < 655360) {
        int rel = id - 262144;
        int k = rel % 768, n = rel / 768;
        Bt2[n * 768 + k] = bf16rne(We1[k * 512 + n]);
    } else if (id < 917504) {
        int rel = id - 655360;
        int k = rel & 511, n = rel >> 9;
        Bt3[n * 512 + k] = bf16rne(We2[k * 512 + n]);
    } else if (id < 925696) {
        int rel = id - 917504;
        int k = rel & 63, n = rel >> 6;     // n<128, k<64
        W1t[n * 64 + k] = bf16rne(W1[k * 128 + n]);
    } else if (id < 1056768) {
        int rel = id - 925696;
        int r = rel >> 6, c = rel & 63;
        float s = bres[c];
#pragma unroll
        for (int i = 0; i < 21; ++i) s += node[r * 21 + i] * Wres[i * 64 + c];
        resfeat[r * 64 + c] = s;
        bufA[(size_t)r * 512 + 448 + c] = s;
    } else if (id < 1974272) {
        int rel = id - 1056768;             // zero agg region: R x 448
        int r = rel / 448, c = rel % 448;
        bufA[(size_t)r * 512 + c] = 0.f;
    } else if (id < 1975296) {
        stats[id - 1974272] = 0.f;
    }
}

// ---------------------------------------------------------------- edge scatter (atomic; proven round-6)
__global__ __launch_bounds__(256) void k_edges(
    const int* __restrict__ esrc, const int* __restrict__ edst,
    const int* __restrict__ erel, const float* __restrict__ resfeat,
    float* __restrict__ bufA)
{
    int idx = blockIdx.x * 256 + threadIdx.x;
    int e = idx >> 6, c = idx & 63;
    int d = edst[e], rel = erel[e], s = esrc[e];
    atomicAdd(&bufA[(size_t)d * 512 + rel * 64 + c], resfeat[s * 64 + c]);
}

// ---------------------------------------------------------------- fused ball query + env; low-LDS, ILP-batched
__global__ __launch_bounds__(256, 6) void k_ball_env(
    const float* __restrict__ pos, const int* __restrict__ ca_idx,
    const int* __restrict__ atom_name,
    const float* __restrict__ emb, const float* __restrict__ Wxyz,
    const unsigned short* __restrict__ W1t,   // [128][64] bf16, read direct from global
    const float* __restrict__ b1,
    const float* __restrict__ W2, const float* __restrict__ b2,
    float* __restrict__ outZ1)
{
    // union buffer: ball phase <=20.5KB; env phase <=15.3KB (overlaps binsw only)
    __shared__ __align__(16) char SB[20736];
    __shared__ int s_list[64];
    __shared__ unsigned s_cnt, s_ccnt;
    __shared__ int sB, sNeed, sB2, sNeed2, sTotal;

    // ball-phase aliases
    unsigned* binsw = (unsigned*)SB;                 // 4096 u32 = 16384B
    unsigned* hist  = (unsigned*)(SB + 16384);       // 256
    unsigned* hist2 = (unsigned*)(SB + 17408);       // 256
    int*      sc    = (int*)(SB + 18432);            // 256
    float*    candd = (float*)(SB + 19456);          // 128
    int*      candi = (int*)(SB + 19968);            // 128 -> 20480

    // env-phase aliases (inside old binsw region, used after ball completes)
    float* pts    = (float*)SB;                      // 48*68 f = 13056B
    float* sWxyz  = (float*)(SB + 13056);            // 192 f -> 13824
    float* s_dv   = (float*)(SB + 13824);            // 144 f -> 14400
    float* env128 = (float*)(SB + 14400);            // 128 f -> 14912
    int*   s_an   = (int*)(SB + 14912);              // 48   -> 15104
    int*   s_aa   = (int*)(SB + 15104);              // 48   -> 15296

    int tid = threadIdx.x;
    int r = blockIdx.x;
    int ca = ca_idx[r];
    float cx = pos[ca * 3 + 0], cy = pos[ca * 3 + 1], cz = pos[ca * 3 + 2];

    hist[tid] = 0u;
    if (tid == 0) { s_cnt = 0u; s_ccnt = 0u; }
    __syncthreads();

    // ---- pass 1: 8 iters x 8 atoms; 6 float4 loads in flight; bins -> LDS uint4
    for (int it = 0; it < 8; ++it) {
        int a0 = it * 2048 + tid * 8;
        const float4* p = (const float4*)(pos + (size_t)a0 * 3);
        float4 pv[6];
#pragma unroll
        for (int j = 0; j < 6; ++j) pv[j] = p[j];
        unsigned pk[2] = { 0u, 0u };
#pragma unroll
        for (int g = 0; g < 2; ++g) {
            float4 p0 = pv[g * 3], p1 = pv[g * 3 + 1], p2 = pv[g * 3 + 2];
            float xs[4] = { p0.x, p0.w, p1.z, p2.y };
            float ys[4] = { p0.y, p1.x, p1.w, p2.z };
            float zs[4] = { p0.z, p1.y, p2.x, p2.w };
#pragma unroll
            for (int q = 0; q < 4; ++q) {
                float d2 = dist2(xs[q], ys[q], zs[q], cx, cy, cz);
                int b = 255;
                if (d2 < 100.0f) {
                    b = (int)(d2 * 2.56f); if (b > 254) b = 254;
                    atomicAdd(&hist[b], 1u);
                }
                pk[g] |= (unsigned)b << (q * 8);
            }
        }
        *(uint2*)&binsw[it * 512 + tid * 2] = make_uint2(pk[0], pk[1]);
    }
    __syncthreads();

    // ---- single-wave inclusive scan of hist (lane t owns bins 4t..4t+3)
    if (tid < 64) {
        int base = tid * 4;
        int v0 = (int)hist[base], v1 = (int)hist[base + 1];
        int v2 = (int)hist[base + 2], v3 = (int)hist[base + 3];
        int loc1 = v0, loc2 = v0 + v1, loc3 = v0 + v1 + v2;
        int s = loc3 + v3;
        int inc = s;
        for (int off = 1; off < 64; off <<= 1) {
            int u = __shfl_up(inc, off);
            if (tid >= off) inc += u;
        }
        int excl = inc - s;
        sc[base] = excl + v0;
        sc[base + 1] = excl + loc1 + v1;
        sc[base + 2] = excl + loc2 + v2;
        sc[base + 3] = excl + loc3 + v3;
    }
    __syncthreads();
    if (tid == 0) sTotal = sc[255];
    if (sc[tid] >= K_ && (tid == 0 || sc[tid - 1] < K_)) {
        sB = tid;
        sNeed = K_ - (sc[tid] - (int)hist[tid]);
    }
    __syncthreads();

    int mode = (sTotal <= K_) ? 0 : (((int)hist[sB] > 128) ? 2 : 1);

    if (mode <= 1) {
        int B = (mode == 0) ? 255 : sB;
        for (int it = 0; it < 8; ++it) {
            uint2 pks = *(const uint2*)&binsw[it * 512 + tid * 2];
            unsigned pkz[2] = { pks.x, pks.y };
            int abase = it * 2048 + tid * 8;
#pragma unroll
            for (int g = 0; g < 2; ++g) {
                int a0 = abase + g * 4;
#pragma unroll
                for (int q = 0; q < 4; ++q) {
                    int b = (pkz[g] >> (q * 8)) & 255;
                    if (b < B) { unsigned pp = atomicAdd(&s_cnt, 1u); s_list[pp] = a0 + q; }
                    else if (b == B && mode == 1) {
                        unsigned c = atomicAdd(&s_ccnt, 1u);
                        if (c < 128u) candi[c] = a0 + q;
                    }
                }
            }
        }
    } else {
        // ---- mode 2 (rare): refine boundary bin; recompute only bin==B atoms
        int B = sB;
        float lo2 = B * 0.390625f;
        hist2[tid] = 0u;
        __syncthreads();
        for (int it = 0; it < 8; ++it) {
            uint2 pks = *(const uint2*)&binsw[it * 512 + tid * 2];
            unsigned pkz[2] = { pks.x, pks.y };
            int abase = it * 2048 + tid * 8;
#pragma unroll
            for (int g = 0; g < 2; ++g) {
#pragma unroll
                for (int q = 0; q < 4; ++q) {
                    if (((pkz[g] >> (q * 8)) & 255) == (unsigned)B) {
                        int a = abase + g * 4 + q;
                        float d2 = dist2(pos[a * 3], pos[a * 3 + 1], pos[a * 3 + 2], cx, cy, cz);
                        int k2 = (int)((d2 - lo2) * 655.36f);
                        if (k2 < 0) k2 = 0; if (k2 > 255) k2 = 255;
                        atomicAdd(&hist2[k2], 1u);
                    }
                }
            }
        }
        __syncthreads();
        if (tid < 64) {
            int base = tid * 4;
            int v0 = (int)hist2[base], v1 = (int)hist2[base + 1];
            int v2 = (int)hist2[base + 2], v3 = (int)hist2[base + 3];
            int loc1 = v0, loc2 = v0 + v1, loc3 = v0 + v1 + v2;
            int s = loc3 + v3;
            int inc = s;
            for (int off = 1; off < 64; off <<= 1) {
                int u = __shfl_up(inc, off);
                if (tid >= off) inc += u;
            }
            int excl = inc - s;
            sc[base] = excl + v0;
            sc[base + 1] = excl + loc1 + v1;
            sc[base + 2] = excl + loc2 + v2;
            sc[base + 3] = excl + loc3 + v3;
        }
        __syncthreads();
        if (sc[tid] >= sNeed && (tid == 0 || sc[tid - 1] < sNeed)) {
            sB2 = tid;
            sNeed2 = sNeed - (sc[tid] - (int)hist2[tid]);
        }
        __syncthreads();
        int B2 = sB2;
        for (int it = 0; it < 8; ++it) {
            uint2 pks = *(const uint2*)&binsw[it * 512 + tid * 2];
            unsigned pkz[2] = { pks.x, pks.y };
            int abase = it * 2048 + tid * 8;
#pragma unroll
            for (int g = 0; g < 2; ++g) {
#pragma unroll
                for (int q = 0; q < 4; ++q) {
                    int b = (pkz[g] >> (q * 8)) & 255;
                    int a = abase + g * 4 + q;
                    if (b < B) { unsigned pp = atomicAdd(&s_cnt, 1u); s_list[pp] = a; }
                    else if (b == B) {
                        float d2 = dist2(pos[a * 3], pos[a * 3 + 1], pos[a * 3 + 2], cx, cy, cz);
                        int k2 = (int)((d2 - lo2) * 655.36f);
                        if (k2 < 0) k2 = 0; if (k2 > 255) k2 = 255;
                        if (k2 < B2) { unsigned pp = atomicAdd(&s_cnt, 1u); s_list[pp] = a; }
                        else if (k2 == B2) {
                            unsigned c = atomicAdd(&s_ccnt, 1u);
                            if (c < 128u) candi[c] = a;
                        }
                    }
                }
            }
        }
    }
    __syncthreads();

    // ---- rank boundary candidates by exact (d, idx)
    int needN = (mode == 0) ? 0 : ((mode == 1) ? sNeed : sNeed2);
    unsigned C = s_ccnt; if (C > 128u) C = 128u;
    if (tid < (int)C) {
        int a = candi[tid];
        float d2 = dist2(pos[a * 3], pos[a * 3 + 1], pos[a * 3 + 2], cx, cy, cz);
        candd[tid] = sqrtf(d2 + 1e-12f);
    }
    __syncthreads();
    if (tid < (int)C) {
        float di = candd[tid]; int ii = candi[tid];
        int rank = 0;
        for (unsigned j = 0; j < C; ++j) {
            float dj = candd[j]; int ij = candi[j];
            if (dj < di || (dj == di && ij < ii)) ++rank;
        }
        if (rank < needN) { unsigned pp = atomicAdd(&s_cnt, 1u); s_list[pp] = ii; }
    }
    __syncthreads();   // ball done: s_list/s_cnt final; SB reusable

    // ================= env phase =================
    unsigned nb = s_cnt;
    if (tid < 192) sWxyz[tid] = Wxyz[tid];
    if (tid < K_) {
        int a = (tid < (int)nb) ? s_list[tid] : -1;
        s_aa[tid] = a;
        if (a >= 0) {
            s_dv[tid * 3 + 0] = pos[a * 3 + 0] - cx;
            s_dv[tid * 3 + 1] = pos[a * 3 + 1] - cy;
            s_dv[tid * 3 + 2] = pos[a * 3 + 2] - cz;
            s_an[tid] = atom_name[a];
        } else {
            s_dv[tid * 3 + 0] = 0.f; s_dv[tid * 3 + 1] = 0.f; s_dv[tid * 3 + 2] = 0.f;
            s_an[tid] = 0;
        }
    }
    __syncthreads();

    // build pts f32 [48][64] (rows padded to 68 floats = 272B)
    for (int idx = tid; idx < K_ * 64; idx += 256) {
        int row = idx >> 6, k = idx & 63;
        int a = s_aa[row];
        float v = 0.f;
        if (a >= 0) {
            v = emb[s_an[row] * 64 + k]
              + s_dv[row * 3 + 0] * sWxyz[k] + s_dv[row * 3 + 1] * sWxyz[64 + k]
              + s_dv[row * 3 + 2] * sWxyz[128 + k];
        }
        pts[row * 68 + k] = v;
    }
    __syncthreads();

    // MFMA: wave w -> output cols 32w..32w+31; W1 fragments read direct from global (L2)
    int w = tid >> 6, l = tid & 63;
    int fr = l & 15, fo = l >> 4;
    f32x4v acc[3][2];
#pragma unroll
    for (int m = 0; m < 3; ++m)
#pragma unroll
        for (int n = 0; n < 2; ++n) acc[m][n] = (f32x4v){0.f, 0.f, 0.f, 0.f};

#pragma unroll
    for (int ks = 0; ks < 2; ++ks) {
        bfrag8 af[3], bf[2];
#pragma unroll
        for (int n = 0; n < 2; ++n) {
            int wrow = (2 * w + n) * 16 + fr;
            bf[n] = *(const bfrag8*)((const char*)W1t + wrow * 128 + ks * 64 + fo * 16);
        }
#pragma unroll
        for (int m = 0; m < 3; ++m) {
            int row = 16 * m + fr;
            const char* base = (const char*)pts + row * 272 + ks * 128 + fo * 32;
            float4 v0 = *(const float4*)base;
            float4 v1 = *(const float4*)(base + 16);
            bfrag8 t;
            t[0] = (short)bf16rne(v0.x); t[1] = (short)bf16rne(v0.y);
            t[2] = (short)bf16rne(v0.z); t[3] = (short)bf16rne(v0.w);
            t[4] = (short)bf16rne(v1.x); t[5] = (short)bf16rne(v1.y);
            t[6] = (short)bf16rne(v1.z); t[7] = (short)bf16rne(v1.w);
            af[m] = t;
        }
#pragma unroll
        for (int m = 0; m < 3; ++m)
#pragma unroll
            for (int n = 0; n < 2; ++n)
                acc[m][n] = __builtin_amdgcn_mfma_f32_16x16x32_bf16(af[m], bf[n], acc[m][n], 0, 0, 0);
    }

    // bias + relu + masked maxpool (D: col=l&15, row=(l>>4)*4+i)
#pragma unroll
    for (int n = 0; n < 2; ++n) {
        int col = 32 * w + n * 16 + fr;
        float bv = b1[col];
        float m = -1e30f;
#pragma unroll
        for (int mt = 0; mt < 3; ++mt) {
#pragma unroll
            for (int i = 0; i < 4; ++i) {
                int row = 16 * mt + fo * 4 + i;
                if (s_aa[row] >= 0) m = fmaxf(m, fmaxf(acc[mt][n][i] + bv, 0.f));
            }
        }
        m = fmaxf(m, __shfl_xor(m, 16));
        m = fmaxf(m, __shfl_xor(m, 32));
        if (fo == 0 && (l & 48) == 0) env128[col] = m;
    }
    __syncthreads();

    // env256 = relu(env128 @ W2 + b2)
    {
        float s = b2[tid];
        for (int i = 0; i < 128; ++i) s += env128[i] * W2[i * 256 + tid];
        outZ1[(size_t)r * 768 + 512 + tid] = fmaxf(s, 0.f);
    }
}

// ---------------------------------------------------------------- bf16 MFMA GEMM, BM=64/BN=64/BK=32 (+BN-input / stats)
template<bool RELU_OUT, bool BN_A, bool STATS>
__global__ __launch_bounds__(256) void k_mgemm(
    const float* __restrict__ A, int lda, int K,
    const unsigned short* __restrict__ Bt,   // [512][K] bf16
    const float* __restrict__ bias,
    const float* __restrict__ stats, const float* __restrict__ gamma,
    const float* __restrict__ beta,
    float* __restrict__ C, int ldc, float* __restrict__ statsOut)
{
    __shared__ __align__(16) unsigned short As[64 * 32];
    __shared__ __align__(16) unsigned short Bs[64 * 32];
    __shared__ float bnsc[BN_A ? 512 : 1];
    __shared__ float bnsh[BN_A ? 512 : 1];

    int tid = threadIdx.x;
    int m0 = blockIdx.y * 64, n0 = blockIdx.x * 64;

    if (BN_A) {
        for (int i = tid; i < 512; i += 256) {
            float mean = stats[i] * (1.0f / 2048.0f);
            float var = stats[512 + i] * (1.0f / 2048.0f) - mean * mean;
            float inv = 1.0f / sqrtf(var + 1e-5f);
            float scv = gamma[i] * inv;
            bnsc[i] = scv;
            bnsh[i] = beta[i] - mean * scv;
        }
        __syncthreads();
    }

    int w = tid >> 6, l = tid & 63;
    int wm = w >> 1, wn = w & 1;

    int ar = tid >> 2, aslot = tid & 3, acg = aslot * 8;
    int abyte = ar * 64 + ((aslot ^ ((ar >> 1) & 3)) << 4);
    int bn_ = tid >> 2, bslot = tid & 3;
    int bbyte = bn_ * 64 + ((bslot ^ ((bn_ >> 1) & 3)) << 4);

    int fr = l & 15, fo = l >> 4;
    int ar0 = 32 * wm + fr, ar1 = ar0 + 16;
    int af0 = ar0 * 64 + ((fo ^ ((ar0 >> 1) & 3)) << 4);
    int af1 = ar1 * 64 + ((fo ^ ((ar1 >> 1) & 3)) << 4);
    int bc0 = 32 * wn + fr, bc1 = bc0 + 16;
    int bf0o = bc0 * 64 + ((fo ^ ((bc0 >> 1) & 3)) << 4);
    int bf1o = bc1 * 64 + ((fo ^ ((bc1 >> 1) & 3)) << 4);

    f32x4v acc00 = {0.f,0.f,0.f,0.f}, acc01 = {0.f,0.f,0.f,0.f};
    f32x4v acc10 = {0.f,0.f,0.f,0.f}, acc11 = {0.f,0.f,0.f,0.f};

    for (int k0 = 0; k0 < K; k0 += 32) {
        const float* ap = A + (size_t)(m0 + ar) * lda + k0 + acg;
        float4 v0 = *(const float4*)ap;
        float4 v1 = *(const float4*)(ap + 4);
        uint4 bv = *(const uint4*)(Bt + (size_t)(n0 + bn_) * K + k0 + bslot * 8);
        if (BN_A) {
            int kb = k0 + acg;
            v0.x = fmaxf(v0.x * bnsc[kb + 0] + bnsh[kb + 0], 0.f);
            v0.y = fmaxf(v0.y * bnsc[kb + 1] + bnsh[kb + 1], 0.f);
            v0.z = fmaxf(v0.z * bnsc[kb + 2] + bnsh[kb + 2], 0.f);
            v0.w = fmaxf(v0.w * bnsc[kb + 3] + bnsh[kb + 3], 0.f);
            v1.x = fmaxf(v1.x * bnsc[kb + 4] + bnsh[kb + 4], 0.f);
            v1.y = fmaxf(v1.y * bnsc[kb + 5] + bnsh[kb + 5], 0.f);
            v1.z = fmaxf(v1.z * bnsc[kb + 6] + bnsh[kb + 6], 0.f);
            v1.w = fmaxf(v1.w * bnsc[kb + 7] + bnsh[kb + 7], 0.f);
        }
        uint4 aw;
        aw.x = (unsigned)bf16rne(v0.x) | ((unsigned)bf16rne(v0.y) << 16);
        aw.y = (unsigned)bf16rne(v0.z) | ((unsigned)bf16rne(v0.w) << 16);
        aw.z = (unsigned)bf16rne(v1.x) | ((unsigned)bf16rne(v1.y) << 16);
        aw.w = (unsigned)bf16rne(v1.z) | ((unsigned)bf16rne(v1.w) << 16);
        __syncthreads();
        *(uint4*)((char*)As + abyte) = aw;
        *(uint4*)((char*)Bs + bbyte) = bv;
        __syncthreads();

        bfrag8 a0 = *(const bfrag8*)((const char*)As + af0);
        bfrag8 a1 = *(const bfrag8*)((const char*)As + af1);
        bfrag8 b0 = *(const bfrag8*)((const char*)Bs + bf0o);
        bfrag8 b1f = *(const bfrag8*)((const char*)Bs + bf1o);
        acc00 = __builtin_amdgcn_mfma_f32_16x16x32_bf16(a0, b0, acc00, 0, 0, 0);
        acc01 = __builtin_amdgcn_mfma_f32_16x16x32_bf16(a0, b1f, acc01, 0, 0, 0);
        acc10 = __builtin_amdgcn_mfma_f32_16x16x32_bf16(a1, b0, acc10, 0, 0, 0);
        acc11 = __builtin_amdgcn_mfma_f32_16x16x32_bf16(a1, b1f, acc11, 0, 0, 0);
    }

    int col0 = n0 + 32 * wn + fr;
    int row0 = m0 + 32 * wm + fo * 4;
    float bb0 = bias[col0], bb1 = bias[col0 + 16];
    float s0 = 0.f, q0 = 0.f, s1 = 0.f, q1 = 0.f;
#pragma unroll
    for (int i = 0; i < 4; ++i) {
        float u00 = acc00[i] + bb0, u01 = acc01[i] + bb1;
        float u10 = acc10[i] + bb0, u11 = acc11[i] + bb1;
        if (RELU_OUT) {
            u00 = fmaxf(u00, 0.f); u01 = fmaxf(u01, 0.f);
            u10 = fmaxf(u10, 0.f); u11 = fmaxf(u11, 0.f);
        }
        if (STATS) {
            s0 += u00 + u10; q0 += u00 * u00 + u10 * u10;
            s1 += u01 + u11; q1 += u01 * u01 + u11 * u11;
        }
        C[(size_t)(row0 + i) * ldc + col0] = u00;
        C[(size_t)(row0 + i) * ldc + col0 + 16] = u01;
        C[(size_t)(row0 + 16 + i) * ldc + col0] = u10;
        C[(size_t)(row0 + 16 + i) * ldc + col0 + 16] = u11;
    }
    if (STATS) {
        s0 += __shfl_xor(s0, 16); s0 += __shfl_xor(s0, 32);
        q0 += __shfl_xor(q0, 16); q0 += __shfl_xor(q0, 32);
        s1 += __shfl_xor(s1, 16); s1 += __shfl_xor(s1, 32);
        q1 += __shfl_xor(q1, 16); q1 += __shfl_xor(q1, 32);
        if (fo == 0) {
            atomicAdd(&statsOut[col0], s0);
            atomicAdd(&statsOut[512 + col0], q0);
            atomicAdd(&statsOut[col0 + 16], s1);
            atomicAdd(&statsOut[512 + col0 + 16], q1);
        }
    }
}

// ---------------------------------------------------------------- launch
extern "C" void kernel_launch(void* const* d_in, const int* in_sizes, int n_in,
                              void* d_out, int out_size, void* d_ws, size_t ws_size,
                              hipStream_t stream)
{
    const float* node   = (const float*)d_in[0];
    const float* pos    = (const float*)d_in[1];
    const int*   aname  = (const int*)d_in[2];
    const int*   caidx  = (const int*)d_in[3];
    const int*   esrc   = (const int*)d_in[4];
    const int*   edst   = (const int*)d_in[5];
    const int*   erel   = (const int*)d_in[6];
    const float* emb    = (const float*)d_in[7];
    const float* Wres   = (const float*)d_in[8];
    const float* bres   = (const float*)d_in[9];
    const float* Wxyz   = (const float*)d_in[10];
    const float* W1     = (const float*)d_in[11];
    const float* b1     = (const float*)d_in[12];
    const float* W2     = (const float*)d_in[13];
    const float* b2     = (const float*)d_in[14];
    const float* Wconv  = (const float*)d_in[15];
    const float* bconv  = (const float*)d_in[16];
    const float* Wself  = (const float*)d_in[17];
    const float* We1    = (const float*)d_in[18];
    const float* be1    = (const float*)d_in[19];
    const float* gamma1 = (const float*)d_in[20];
    const float* beta1  = (const float*)d_in[21];
    const float* We2    = (const float*)d_in[22];
    const float* be2    = (const float*)d_in[23];
    float* out = (float*)d_out;

    char* ws = (char*)d_ws;
    float* resfeat = (float*)(ws + 0);                       // R*64 f32 (512KB)
    float* bufA    = (float*)(ws + 524288);                  // R*512 f32 (4MB)
    float* bufZ1   = (float*)(ws + 4718592);                 // R*768 f32 (6MB)
    float* bufZ2   = (float*)(ws + 11010048);                // R*512 f32 (4MB)
    float* stats   = (float*)(ws + 15204352);                // 1024 f32
    unsigned short* Bt1 = (unsigned short*)(ws + 15208448);  // 512x512 bf16
    unsigned short* Bt2 = (unsigned short*)(ws + 15732736);  // 512x768 bf16
    unsigned short* Bt3 = (unsigned short*)(ws + 16519168);  // 512x512 bf16
    unsigned short* W1t = (unsigned short*)(ws + 17043456);  // 128x64 bf16

    k_prep<<<7716, 256, 0, stream>>>(Wconv, Wself, We1, We2, W1, node, Wres, bres,
                                     Bt1, Bt2, Bt3, W1t, resfeat, bufA, stats);
    k_ball_env<<<R_, 256, 0, stream>>>(pos, caidx, aname, emb, Wxyz, W1t, b1, W2, b2, bufZ1);
    k_edges<<<(size_t)E_ * 64 / 256, 256, 0, stream>>>(esrc, edst, erel, resfeat, bufA);

    dim3 gg(512 / 64, R_ / 64);
    k_mgemm<true, false, false><<<gg, 256, 0, stream>>>(
        bufA, 512, 512, Bt1, bconv, nullptr, nullptr, nullptr, bufZ1, 768, nullptr);
    k_mgemm<false, false, true><<<gg, 256, 0, stream>>>(
        bufZ1, 768, 768, Bt2, be1, nullptr, nullptr, nullptr, bufZ2, 512, stats);
    k_mgemm<false, true, false><<<gg, 256, 0, stream>>>(
        bufZ2, 512, 512, Bt3, be2, stats, gamma1, beta1, out, 512, nullptr);
}